// Round 1
// 3148.057 us; speedup vs baseline: 1.5083x; 1.5083x over previous
//
#include <hip/hip_runtime.h>

typedef short bf16x8 __attribute__((ext_vector_type(8)));
typedef float f32x4 __attribute__((ext_vector_type(4)));
typedef unsigned short ushort_t;

__device__ inline float bf2f(ushort_t h) {
    return __uint_as_float(((unsigned int)h) << 16);
}
__device__ inline ushort_t f2bf(float f) {
    unsigned int u = __float_as_uint(f);
    unsigned int r = u + 0x7fffu + ((u >> 16) & 1u);   // RNE
    return (ushort_t)(r >> 16);
}

// async global->LDS, 16B per lane, LDS dest = wave-uniform base + lane*16
__device__ __forceinline__ void gload16(const ushort_t* g, ushort_t* l) {
    __builtin_amdgcn_global_load_lds(
        (const __attribute__((address_space(1))) unsigned int*)g,
        (__attribute__((address_space(3))) unsigned int*)l,
        16, 0, 0);
}

// ---------------------------------------------------------------------------
// fp32 -> bf16 bulk convert, 8 elems/thread/iter, grid-stride.
// ---------------------------------------------------------------------------
__global__ __launch_bounds__(256) void cvt_bf16(
    const float* __restrict__ s, ushort_t* __restrict__ d, long long n8)
{
    long long i = (long long)blockIdx.x * 256 + threadIdx.x;
    const long long stride = (long long)gridDim.x * 256;
    for (; i < n8; i += stride) {
        const float4 a = ((const float4*)s)[2 * i];
        const float4 b = ((const float4*)s)[2 * i + 1];
        uint4 o;
        o.x = (unsigned)f2bf(a.x) | ((unsigned)f2bf(a.y) << 16);
        o.y = (unsigned)f2bf(a.z) | ((unsigned)f2bf(a.w) << 16);
        o.z = (unsigned)f2bf(b.x) | ((unsigned)f2bf(b.y) << 16);
        o.w = (unsigned)f2bf(b.z) | ((unsigned)f2bf(b.w) << 16);
        ((uint4*)d)[i] = o;
    }
}

// ---------------------------------------------------------------------------
// C = A(MxK,bf16) * W(NxK,bf16)^T, bf16 MFMA, fp32 accumulate. K = 4096.
// m97 structure: 128x128 tile, BK=64, 256 threads, linear LDS,
// global_load_lds width=16, 2-barrier K-loop. Bijective XCD-chunk swizzle.
// roff: global row offset (A may be an M-chunk of the logical matrix).
// dest modes: 0 plain bf16 r*ldc+c; 1 ctx-cache bf16 (b=r>>12,t=r&4095 ->
//   (b*4160+t)*1024+c); 2 noise-cache bf16 (b=r>>6,k=r&63 ->
//   (b*4160+4096+k)*1024+c); 3 plain fp32 r*ldc+c.
// ---------------------------------------------------------------------------
__global__ __launch_bounds__(256) void gemm_bt_bf16(
    const ushort_t* __restrict__ A, int roff,
    const ushort_t* __restrict__ W0, void* __restrict__ D0, int nb0, int mode0, int ldc0,
    const ushort_t* __restrict__ W1, void* __restrict__ D1, int nb1, int mode1, int ldc1,
    const ushort_t* __restrict__ W2, void* __restrict__ D2, int mode2, int ldc2)
{
    __shared__ __align__(16) ushort_t As[128 * 64];
    __shared__ __align__(16) ushort_t Bs[128 * 64];

    const int tid = threadIdx.x;
    const int lane = tid & 63;
    const int wid = tid >> 6;
    const int quad = lane >> 4;

    // bijective XCD-chunk swizzle (m204): blocks sharing an A-tile -> one XCD
    const int gx = (int)gridDim.x;
    const int nwg = gx * (int)gridDim.y;
    const int flat = (int)blockIdx.y * gx + (int)blockIdx.x;
    const int q = nwg >> 3, r = nwg & 7;
    const int xcd = flat & 7, off = flat >> 3;
    const int lin = (xcd < r ? xcd * (q + 1) : r * (q + 1) + (xcd - r) * q) + off;
    const int bn = lin % gx;
    const int bm = lin / gx;

    const ushort_t* W; void* D; int mode, ldc, nloc;
    if (bn < nb0)            { W = W0; D = D0; mode = mode0; ldc = ldc0; nloc = bn; }
    else if (bn < nb0 + nb1) { W = W1; D = D1; mode = mode1; ldc = ldc1; nloc = bn - nb0; }
    else                     { W = W2; D = D2; mode = mode2; ldc = ldc2; nloc = bn - nb0 - nb1; }

    const int wm = wid >> 1, wn = wid & 1;
    const int srow = lane >> 3;          // row within 8-row LDS chunk
    const int scol = (lane & 7) * 8;     // bf16 col within BK=64

    f32x4 acc[4][4];
    for (int mt = 0; mt < 4; mt++)
        for (int nt = 0; nt < 4; nt++)
            acc[mt][nt] = (f32x4)0.0f;

    for (int k0 = 0; k0 < 4096; k0 += 64) {
        __syncthreads();
        for (int i = 0; i < 4; i++) {
            const int chunk = wid * 4 + i;          // 0..15 (1 KB LDS each)
            const int row = chunk * 8 + srow;       // 0..127
            gload16(A + (size_t)(bm * 128 + row) * 4096 + k0 + scol, &As[chunk * 512]);
            gload16(W + (size_t)(nloc * 128 + row) * 4096 + k0 + scol, &Bs[chunk * 512]);
        }
        __syncthreads();
        for (int kk = 0; kk < 2; kk++) {
            const int c16b = kk * 4 + quad;
            bf16x8 af[4], bfv[4];
            for (int mt = 0; mt < 4; mt++) {
                const int rm = wm * 64 + mt * 16 + (lane & 15);
                af[mt] = *(const bf16x8*)&As[rm * 64 + c16b * 8];
            }
            for (int nt = 0; nt < 4; nt++) {
                const int rn = wn * 64 + nt * 16 + (lane & 15);
                bfv[nt] = *(const bf16x8*)&Bs[rn * 64 + c16b * 8];
            }
            for (int mt = 0; mt < 4; mt++)
                for (int nt = 0; nt < 4; nt++)
                    acc[mt][nt] = __builtin_amdgcn_mfma_f32_16x16x32_bf16(
                        af[mt], bfv[nt], acc[mt][nt], 0, 0, 0);
        }
    }

    for (int mt = 0; mt < 4; mt++) {
        for (int nt = 0; nt < 4; nt++) {
            const int c = nloc * 128 + wn * 64 + nt * 16 + (lane & 15);
            for (int rr = 0; rr < 4; rr++) {
                const int r = roff + bm * 128 + wm * 64 + mt * 16 + quad * 4 + rr;
                const float val = acc[mt][nt][rr];
                if (mode == 0) {
                    ((ushort_t*)D)[(size_t)r * ldc + c] = f2bf(val);
                } else if (mode == 1) {
                    int b = r >> 12, t = r & 4095;
                    ((ushort_t*)D)[((size_t)(b * 4160 + t)) * 1024 + c] = f2bf(val);
                } else if (mode == 2) {
                    int b = r >> 6, kq = r & 63;
                    ((ushort_t*)D)[((size_t)(b * 4160 + 4096 + kq)) * 1024 + c] = f2bf(val);
                } else {
                    ((float*)D)[(size_t)r * ldc + c] = val;
                }
            }
        }
    }
}

// ---------------------------------------------------------------------------
// RMSNorm + RoPE, in place on bf16 buffers, one wave per 128-dim head row.
// ---------------------------------------------------------------------------
__global__ __launch_bounds__(256) void norm_rope(
    ushort_t* __restrict__ X,
    const float* __restrict__ cosb, const float* __restrict__ sinb,
    const float* __restrict__ w, int mode)
{
    const int lane = threadIdx.x & 63;
    const int wid = threadIdx.x >> 6;
    const int rid = blockIdx.x * 4 + wid;

    ushort_t* ptr;
    size_t pos_row;
    if (mode == 0) {
        const int h = rid & 7, tmp = rid >> 3;      // tmp = b*4160 + l
        ptr = X + (size_t)tmp * 1024 + h * 128;
        pos_row = (size_t)tmp;
    } else {
        const int h = rid & 31, tmp = rid >> 5;     // tmp = b*64 + k
        const int k = tmp & 63, b = tmp >> 6;
        ptr = X + (size_t)tmp * 4096 + h * 128;
        pos_row = (size_t)(b * 4160 + 4096 + k);
    }

    float x1 = bf2f(ptr[lane]);
    float x2 = bf2f(ptr[lane + 64]);
    float ss = x1 * x1 + x2 * x2;
    for (int m = 1; m < 64; m <<= 1) ss += __shfl_xor(ss, m, 64);
    const float rn = rsqrtf(ss * (1.0f / 128.0f) + 1e-6f);
    const float y1 = x1 * rn * w[lane];
    const float y2 = x2 * rn * w[lane + 64];

    const float* cr = cosb + pos_row * 128;
    const float* sr = sinb + pos_row * 128;
    ptr[lane]      = f2bf(y1 * cr[lane]      - y2 * sr[lane]);
    ptr[lane + 64] = f2bf(y2 * cr[lane + 64] + y1 * sr[lane + 64]);
}

// ---------------------------------------------------------------------------
// Flash attention: one block = (b, head h, 32-query half), 256 blocks, 256 thr.
// Output AO now bf16 (final GEMM consumed it as bf16 anyway).
// ---------------------------------------------------------------------------
__global__ __launch_bounds__(256) void attn_kernel(
    const ushort_t* __restrict__ Qb, const ushort_t* __restrict__ Kc,
    const ushort_t* __restrict__ Vc, const float* __restrict__ amask,
    ushort_t* __restrict__ AO)
{
    __shared__ __align__(16) ushort_t Qs[32 * 136];
    __shared__ __align__(16) ushort_t Ks[128 * 136];
    __shared__ __align__(16) ushort_t Vts[128 * 136];   // transposed: [d][l]
    __shared__ __align__(16) ushort_t Ps[32 * 136];
    __shared__ __align__(16) float Ss[32 * 132];
    __shared__ float mst[32], lst[32], alp[32];

    const int tid = threadIdx.x;
    const int lane = tid & 63;
    const int wid = tid >> 6;
    const int quad = lane >> 4;

    const int bidx = blockIdx.x;
    const int b = bidx >> 6;
    const int rb = bidx & 63;
    const int h = rb >> 1;
    const int k0 = (rb & 1) * 32;
    const int hkv = h >> 2;

    // stage Q tile (32 queries x 128)
    {
        const int row = tid >> 3, j = tid & 7;
        const ushort_t* src = Qb + ((size_t)(b * 64 + k0 + row) * 4096 + h * 128 + j * 16);
        uint4 v0 = *(const uint4*)src;
        uint4 v1 = *(const uint4*)(src + 8);
        *(uint4*)&Qs[row * 136 + j * 16] = v0;
        *(uint4*)&Qs[row * 136 + j * 16 + 8] = v1;
    }
    if (tid < 32) { mst[tid] = -INFINITY; lst[tid] = 0.0f; }
    __syncthreads();

    bf16x8 aq[2][4];
    for (int mt = 0; mt < 2; mt++)
        for (int kk = 0; kk < 4; kk++)
            aq[mt][kk] = *(const bf16x8*)&Qs[(mt * 16 + (lane & 15)) * 136 + kk * 32 + quad * 8];

    f32x4 acc_o[2][2];
    for (int mt = 0; mt < 2; mt++)
        for (int nt = 0; nt < 2; nt++)
            acc_o[mt][nt] = (f32x4)0.0f;

    const float scale = 0.08838834764831845f;  // 1/sqrt(128)
    const int n0w = wid * 32;
    const int d0w = wid * 32;

    for (int ch = 0; ch < 33; ch++) {
        const int l0 = ch * 128;
        __syncthreads();

        // stage K chunk (128 l-rows x 128 d)
        {
            const int row = tid >> 1, half = tid & 1;
            const int lg = l0 + row;
            const ushort_t* src = Kc + ((size_t)(b * 4160 + lg) * 1024 + hkv * 128);
            const bool ok = lg < 4160;
            for (int i = 0; i < 8; i++) {
                const int ci = i * 2 + half;
                uint4 v = ok ? *(const uint4*)(src + ci * 8) : make_uint4(0, 0, 0, 0);
                *(uint4*)&Ks[row * 136 + ci * 8] = v;
            }
        }
        // stage V chunk transposed: Vts[d][l]
        for (int it = 0; it < 4; it++) {
            const int dg = wid + 4 * it;
            const int l = l0 + 2 * lane;
            const ushort_t* src = Vc + ((size_t)(b * 4160 + l) * 1024 + hkv * 128 + dg * 8);
            uint4 va = make_uint4(0, 0, 0, 0), vb = make_uint4(0, 0, 0, 0);
            if (l < 4160)     va = *(const uint4*)src;
            if (l + 1 < 4160) vb = *(const uint4*)(src + 1024);
            const ushort_t* ap = (const ushort_t*)&va;
            const ushort_t* bp = (const ushort_t*)&vb;
            for (int jj = 0; jj < 8; jj++) {
                unsigned int val = (unsigned int)ap[jj] | ((unsigned int)bp[jj] << 16);
                *(unsigned int*)&Vts[(dg * 8 + jj) * 136 + 2 * lane] = val;
            }
        }
        __syncthreads();

        // S = Q K^T
        f32x4 sacc[2][2];
        for (int mt = 0; mt < 2; mt++)
            for (int nt = 0; nt < 2; nt++)
                sacc[mt][nt] = (f32x4)0.0f;
        for (int kk = 0; kk < 4; kk++) {
            bf16x8 bk_[2];
            for (int nt = 0; nt < 2; nt++)
                bk_[nt] = *(const bf16x8*)&Ks[(n0w + nt * 16 + (lane & 15)) * 136 + kk * 32 + quad * 8];
            for (int mt = 0; mt < 2; mt++)
                for (int nt = 0; nt < 2; nt++)
                    sacc[mt][nt] = __builtin_amdgcn_mfma_f32_16x16x32_bf16(
                        aq[mt][kk], bk_[nt], sacc[mt][nt], 0, 0, 0);
        }
        for (int mt = 0; mt < 2; mt++) {
            for (int nt = 0; nt < 2; nt++) {
                const int col = n0w + nt * 16 + (lane & 15);
                const int l = l0 + col;
                for (int rr = 0; rr < 4; rr++) {
                    const int row = mt * 16 + quad * 4 + rr;
                    float s;
                    if (l < 4160) {
                        const float mk = amask[(size_t)(b * 64 + k0 + row) * 4160 + l];
                        s = sacc[mt][nt][rr] * scale + mk;
                    } else s = -3.0e4f;
                    Ss[row * 132 + col] = s;
                }
            }
        }
        __syncthreads();

        // online softmax: 8 lanes per row, 16 cols per lane
        {
            const int rw = wid * 8 + (lane >> 3);
            const int j = lane & 7;
            const float* srow = &Ss[rw * 132 + j * 16];
            float v[16];
            float mx = -INFINITY;
            for (int jj = 0; jj < 16; jj++) { v[jj] = srow[jj]; mx = fmaxf(mx, v[jj]); }
            mx = fmaxf(mx, __shfl_xor(mx, 1, 64));
            mx = fmaxf(mx, __shfl_xor(mx, 2, 64));
            mx = fmaxf(mx, __shfl_xor(mx, 4, 64));
            const float mo = mst[rw];
            const float mn = fmaxf(mo, mx);
            float sum = 0.0f;
            ushort_t pv[16];
            for (int jj = 0; jj < 16; jj++) {
                const float p = __expf(v[jj] - mn);
                sum += p;
                pv[jj] = f2bf(p);
            }
            sum += __shfl_xor(sum, 1, 64);
            sum += __shfl_xor(sum, 2, 64);
            sum += __shfl_xor(sum, 4, 64);
            const float a_ = __expf(mo - mn);
            if (j == 0) { mst[rw] = mn; lst[rw] = lst[rw] * a_ + sum; alp[rw] = a_; }
            for (int jj = 0; jj < 16; jj += 2) {
                unsigned int pk = (unsigned int)pv[jj] | ((unsigned int)pv[jj + 1] << 16);
                *(unsigned int*)&Ps[rw * 136 + j * 16 + jj] = pk;
            }
        }
        __syncthreads();

        // O = O*alpha + P V
        for (int mt = 0; mt < 2; mt++) {
            for (int nt = 0; nt < 2; nt++) {
                for (int rr = 0; rr < 4; rr++) {
                    const int row = mt * 16 + quad * 4 + rr;
                    acc_o[mt][nt][rr] *= alp[row];
                }
            }
        }
        for (int kk = 0; kk < 4; kk++) {
            bf16x8 ap_[2], bv[2];
            for (int mt = 0; mt < 2; mt++)
                ap_[mt] = *(const bf16x8*)&Ps[(mt * 16 + (lane & 15)) * 136 + kk * 32 + quad * 8];
            for (int nt = 0; nt < 2; nt++)
                bv[nt] = *(const bf16x8*)&Vts[(d0w + nt * 16 + (lane & 15)) * 136 + kk * 32 + quad * 8];
            for (int mt = 0; mt < 2; mt++)
                for (int nt = 0; nt < 2; nt++)
                    acc_o[mt][nt] = __builtin_amdgcn_mfma_f32_16x16x32_bf16(
                        ap_[mt], bv[nt], acc_o[mt][nt], 0, 0, 0);
        }
    }

    // epilogue: divide by l, store bf16 to AO (b,k, h*128+d)
    for (int mt = 0; mt < 2; mt++) {
        for (int nt = 0; nt < 2; nt++) {
            const int col = d0w + nt * 16 + (lane & 15);
            for (int rr = 0; rr < 4; rr++) {
                const int row = mt * 16 + quad * 4 + rr;
                AO[(size_t)(b * 64 + k0 + row) * 4096 + h * 128 + col] =
                    f2bf(acc_o[mt][nt][rr] / lst[row]);
            }
        }
    }
}

// ---------------------------------------------------------------------------

extern "C" void kernel_launch(void* const* d_in, const int* in_sizes, int n_in,
                              void* d_out, int out_size, void* d_ws, size_t ws_size,
                              hipStream_t stream) {
    const float* hs    = (const float*)d_in[0];   // hidden_states (4,64,4096) fp32
    const float* th    = (const float*)d_in[1];   // target_hidden (4,4096,4096) fp32
    const float* amask = (const float*)d_in[2];   // attn_mask (4,1,64,4160) fp32
    const float* cosb  = (const float*)d_in[3];   // cos (4,4160,128) fp32
    const float* sinb  = (const float*)d_in[4];   // sin fp32
    const float* Wq    = (const float*)d_in[5];   // (4096,4096) fp32
    const float* Wk    = (const float*)d_in[6];   // (1024,4096) fp32
    const float* Wv    = (const float*)d_in[7];   // (1024,4096) fp32
    const float* Wo    = (const float*)d_in[8];   // (4096,4096) fp32
    const float* qw    = (const float*)d_in[9];   // (128,) fp32
    const float* kw    = (const float*)d_in[10];  // (128,) fp32
    float* out = (float*)d_out;                   // (4,64,4096) fp32

    char* ws = (char*)d_ws;
    size_t off = 0;
    auto alloc = [&](size_t b) { char* p = ws + off; off += (b + 255) & ~(size_t)255; return p; };
    ushort_t* Kc  = (ushort_t*)alloc(34078720);   // (4,4160,1024) bf16
    ushort_t* Vc  = (ushort_t*)alloc(34078720);
    ushort_t* Qb  = (ushort_t*)alloc(2097152);    // (256,4096) bf16
    ushort_t* AOb = (ushort_t*)alloc(2097152);    // (256,4096) bf16
    ushort_t* hsb = (ushort_t*)alloc(2097152);    // hs bf16
    ushort_t* Wqb = (ushort_t*)alloc(33554432);
    ushort_t* Wkb = (ushort_t*)alloc(8388608);
    ushort_t* Wvb = (ushort_t*)alloc(8388608);
    ushort_t* Wob = (ushort_t*)alloc(33554432);

    // th bf16 staging: full buffer if workspace allows, else M-chunked
    int mrows;
    if      (ws_size >= off + (size_t)134217728) mrows = 16384;  // full (16384,4096)
    else if (ws_size >= off + (size_t)33554432)  mrows = 4096;   // 4 chunks
    else                                         mrows = 2048;   // 8 chunks
    ushort_t* thb = (ushort_t*)alloc((size_t)mrows * 4096 * 2);

    // 0) one-time bf16 conversions (weights + hs)
    cvt_bf16<<<dim3(1024), 256, 0, stream>>>(Wk, Wkb, 1024LL * 4096 / 8);
    cvt_bf16<<<dim3(1024), 256, 0, stream>>>(Wv, Wvb, 1024LL * 4096 / 8);
    cvt_bf16<<<dim3(2048), 256, 0, stream>>>(Wq, Wqb, 4096LL * 4096 / 8);
    cvt_bf16<<<dim3(2048), 256, 0, stream>>>(Wo, Wob, 4096LL * 4096 / 8);
    cvt_bf16<<<dim3(512),  256, 0, stream>>>(hs, hsb, 256LL * 4096 / 8);

    // 1) ctx K and V projections (dominant GEMM), bf16 path, chunked over M
    for (int c = 0; c < 16384 / mrows; ++c) {
        cvt_bf16<<<dim3(2048), 256, 0, stream>>>(
            th + (size_t)c * mrows * 4096, thb, (long long)mrows * 4096 / 8);
        gemm_bt_bf16<<<dim3(16, mrows / 128), 256, 0, stream>>>(thb, c * mrows,
            Wkb, Kc, 8, 1, 0,
            Wvb, Vc, 8, 1, 0,
            Wvb, Vc, 1, 0);
    }
    // 2) noise Q / K / V projections
    gemm_bt_bf16<<<dim3(48, 2), 256, 0, stream>>>(hsb, 0,
        Wqb, Qb, 32, 0, 4096,
        Wkb, Kc, 8, 2, 0,
        Wvb, Vc, 2, 0);
    // 3) rmsnorm + rope on K cache (all 4160 positions) and Q
    norm_rope<<<33280, 256, 0, stream>>>(Kc, cosb, sinb, kw, 0);
    norm_rope<<<2048, 256, 0, stream>>>(Qb, cosb, sinb, qw, 1);
    // 4) flash attention (bf16 output)
    attn_kernel<<<256, 256, 0, stream>>>(Qb, Kc, Vc, amask, AOb);
    // 5) output projection (bf16 A, fp32 out)
    gemm_bt_bf16<<<dim3(32, 2), 256, 0, stream>>>(AOb, 0,
        Wob, out, 32, 3, 4096,
        Wob, out, 0, 3, 4096,
        Wob, out, 3, 4096);
}

// Round 2
// 2937.625 us; speedup vs baseline: 1.6163x; 1.0716x over previous
//
#include <hip/hip_runtime.h>

typedef short bf16x8 __attribute__((ext_vector_type(8)));
typedef float f32x4 __attribute__((ext_vector_type(4)));
typedef unsigned short ushort_t;

__device__ inline float bf2f(ushort_t h) {
    return __uint_as_float(((unsigned int)h) << 16);
}
__device__ inline ushort_t f2bf(float f) {
    unsigned int u = __float_as_uint(f);
    unsigned int r = u + 0x7fffu + ((u >> 16) & 1u);   // RNE
    return (ushort_t)(r >> 16);
}

// async global->LDS, 16B per lane, LDS dest = wave-uniform base + lane*16
__device__ __forceinline__ void gload16(const ushort_t* g, ushort_t* l) {
    __builtin_amdgcn_global_load_lds(
        (const __attribute__((address_space(1))) unsigned int*)g,
        (__attribute__((address_space(3))) unsigned int*)l,
        16, 0, 0);
}

// ---------------------------------------------------------------------------
// fp32 -> bf16 bulk convert, 8 elems/thread/iter, grid-stride.
// ---------------------------------------------------------------------------
__global__ __launch_bounds__(256) void cvt_bf16(
    const float* __restrict__ s, ushort_t* __restrict__ d, long long n8)
{
    long long i = (long long)blockIdx.x * 256 + threadIdx.x;
    const long long stride = (long long)gridDim.x * 256;
    for (; i < n8; i += stride) {
        const float4 a = ((const float4*)s)[2 * i];
        const float4 b = ((const float4*)s)[2 * i + 1];
        uint4 o;
        o.x = (unsigned)f2bf(a.x) | ((unsigned)f2bf(a.y) << 16);
        o.y = (unsigned)f2bf(a.z) | ((unsigned)f2bf(a.w) << 16);
        o.z = (unsigned)f2bf(b.x) | ((unsigned)f2bf(b.y) << 16);
        o.w = (unsigned)f2bf(b.z) | ((unsigned)f2bf(b.w) << 16);
        ((uint4*)d)[i] = o;
    }
}

// ---------------------------------------------------------------------------
// C = A(MxK,bf16) * W(NxK,bf16)^T, bf16 MFMA, fp32 accumulate. K = 4096.
// m97 structure: 128x128 tile, BK=64, 256 threads, global_load_lds width=16.
// LDS XOR swizzle via PRE-SWIZZLED GLOBAL SOURCE (rule #21 / m201 pattern):
//   lane l stages source chunk (l&7)^(l>>3), so LDS slot s of row r holds
//   chunk s^(r&7); reads use slot c16b^(rm&7). Linear LDS dest (gload req).
// __launch_bounds__(256,2): cap 256 VGPR/wave -> accumulator cannot spill.
// dest modes: 0 plain bf16 r*ldc+c; 1 ctx-cache bf16 (b=r>>12,t=r&4095 ->
//   (b*4160+t)*1024+c); 2 noise-cache bf16 (b=r>>6,k=r&63 ->
//   (b*4160+4096+k)*1024+c); 3 plain fp32 r*ldc+c.
// ---------------------------------------------------------------------------
__global__ __launch_bounds__(256, 2) void gemm_bt_bf16(
    const ushort_t* __restrict__ A, int roff,
    const ushort_t* __restrict__ W0, void* __restrict__ D0, int nb0, int mode0, int ldc0,
    const ushort_t* __restrict__ W1, void* __restrict__ D1, int nb1, int mode1, int ldc1,
    const ushort_t* __restrict__ W2, void* __restrict__ D2, int mode2, int ldc2)
{
    __shared__ __align__(16) ushort_t As[128 * 64];
    __shared__ __align__(16) ushort_t Bs[128 * 64];

    const int tid = threadIdx.x;
    const int lane = tid & 63;
    const int wid = tid >> 6;
    const int quad = lane >> 4;

    // bijective XCD-chunk swizzle (m204): blocks sharing an A-tile -> one XCD
    const int gx = (int)gridDim.x;
    const int nwg = gx * (int)gridDim.y;
    const int flat = (int)blockIdx.y * gx + (int)blockIdx.x;
    const int q = nwg >> 3, r = nwg & 7;
    const int xcd = flat & 7, off = flat >> 3;
    const int lin = (xcd < r ? xcd * (q + 1) : r * (q + 1) + (xcd - r) * q) + off;
    const int bn = lin % gx;
    const int bm = lin / gx;

    const ushort_t* W; void* D; int mode, ldc, nloc;
    if (bn < nb0)            { W = W0; D = D0; mode = mode0; ldc = ldc0; nloc = bn; }
    else if (bn < nb0 + nb1) { W = W1; D = D1; mode = mode1; ldc = ldc1; nloc = bn - nb0; }
    else                     { W = W2; D = D2; mode = mode2; ldc = ldc2; nloc = bn - nb0 - nb1; }

    const int wm = wid >> 1, wn = wid & 1;
    const int srow = lane >> 3;                    // row within 8-row LDS chunk
    const int scs  = ((lane & 7) ^ srow) * 8;      // swizzled source col (bf16 units)

    f32x4 acc[4][4];
    for (int mt = 0; mt < 4; mt++)
        for (int nt = 0; nt < 4; nt++)
            acc[mt][nt] = (f32x4)0.0f;

    for (int k0 = 0; k0 < 4096; k0 += 64) {
        __syncthreads();
        for (int i = 0; i < 4; i++) {
            const int chunk = wid * 4 + i;          // 0..15 (1 KB LDS each)
            const int row = chunk * 8 + srow;       // 0..127
            gload16(A + (size_t)(bm * 128 + row) * 4096 + k0 + scs, &As[chunk * 512]);
            gload16(W + (size_t)(nloc * 128 + row) * 4096 + k0 + scs, &Bs[chunk * 512]);
        }
        __syncthreads();
        for (int kk = 0; kk < 2; kk++) {
            const int c16b = kk * 4 + quad;
            bf16x8 af[4], bfv[4];
            for (int mt = 0; mt < 4; mt++) {
                const int rm = wm * 64 + mt * 16 + (lane & 15);
                af[mt] = *(const bf16x8*)&As[rm * 64 + ((c16b ^ (rm & 7)) * 8)];
            }
            for (int nt = 0; nt < 4; nt++) {
                const int rn = wn * 64 + nt * 16 + (lane & 15);
                bfv[nt] = *(const bf16x8*)&Bs[rn * 64 + ((c16b ^ (rn & 7)) * 8)];
            }
            for (int mt = 0; mt < 4; mt++)
                for (int nt = 0; nt < 4; nt++)
                    acc[mt][nt] = __builtin_amdgcn_mfma_f32_16x16x32_bf16(
                        af[mt], bfv[nt], acc[mt][nt], 0, 0, 0);
        }
    }

    for (int mt = 0; mt < 4; mt++) {
        for (int nt = 0; nt < 4; nt++) {
            const int c = nloc * 128 + wn * 64 + nt * 16 + (lane & 15);
            for (int rr = 0; rr < 4; rr++) {
                const int r = roff + bm * 128 + wm * 64 + mt * 16 + quad * 4 + rr;
                const float val = acc[mt][nt][rr];
                if (mode == 0) {
                    ((ushort_t*)D)[(size_t)r * ldc + c] = f2bf(val);
                } else if (mode == 1) {
                    int b = r >> 12, t = r & 4095;
                    ((ushort_t*)D)[((size_t)(b * 4160 + t)) * 1024 + c] = f2bf(val);
                } else if (mode == 2) {
                    int b = r >> 6, kq = r & 63;
                    ((ushort_t*)D)[((size_t)(b * 4160 + 4096 + kq)) * 1024 + c] = f2bf(val);
                } else {
                    ((float*)D)[(size_t)r * ldc + c] = val;
                }
            }
        }
    }
}

// ---------------------------------------------------------------------------
// RMSNorm + RoPE, in place on bf16 buffers, one wave per 128-dim head row.
// ---------------------------------------------------------------------------
__global__ __launch_bounds__(256) void norm_rope(
    ushort_t* __restrict__ X,
    const float* __restrict__ cosb, const float* __restrict__ sinb,
    const float* __restrict__ w, int mode)
{
    const int lane = threadIdx.x & 63;
    const int wid = threadIdx.x >> 6;
    const int rid = blockIdx.x * 4 + wid;

    ushort_t* ptr;
    size_t pos_row;
    if (mode == 0) {
        const int h = rid & 7, tmp = rid >> 3;      // tmp = b*4160 + l
        ptr = X + (size_t)tmp * 1024 + h * 128;
        pos_row = (size_t)tmp;
    } else {
        const int h = rid & 31, tmp = rid >> 5;     // tmp = b*64 + k
        const int k = tmp & 63, b = tmp >> 6;
        ptr = X + (size_t)tmp * 4096 + h * 128;
        pos_row = (size_t)(b * 4160 + 4096 + k);
    }

    float x1 = bf2f(ptr[lane]);
    float x2 = bf2f(ptr[lane + 64]);
    float ss = x1 * x1 + x2 * x2;
    for (int m = 1; m < 64; m <<= 1) ss += __shfl_xor(ss, m, 64);
    const float rn = rsqrtf(ss * (1.0f / 128.0f) + 1e-6f);
    const float y1 = x1 * rn * w[lane];
    const float y2 = x2 * rn * w[lane + 64];

    const float* cr = cosb + pos_row * 128;
    const float* sr = sinb + pos_row * 128;
    ptr[lane]      = f2bf(y1 * cr[lane]      - y2 * sr[lane]);
    ptr[lane + 64] = f2bf(y2 * cr[lane + 64] + y1 * sr[lane + 64]);
}

// ---------------------------------------------------------------------------
// Flash attention: one block = (b, head h, 32-query half), 256 blocks, 256 thr.
// Output AO bf16.
// ---------------------------------------------------------------------------
__global__ __launch_bounds__(256) void attn_kernel(
    const ushort_t* __restrict__ Qb, const ushort_t* __restrict__ Kc,
    const ushort_t* __restrict__ Vc, const float* __restrict__ amask,
    ushort_t* __restrict__ AO)
{
    __shared__ __align__(16) ushort_t Qs[32 * 136];
    __shared__ __align__(16) ushort_t Ks[128 * 136];
    __shared__ __align__(16) ushort_t Vts[128 * 136];   // transposed: [d][l]
    __shared__ __align__(16) ushort_t Ps[32 * 136];
    __shared__ __align__(16) float Ss[32 * 132];
    __shared__ float mst[32], lst[32], alp[32];

    const int tid = threadIdx.x;
    const int lane = tid & 63;
    const int wid = tid >> 6;
    const int quad = lane >> 4;

    const int bidx = blockIdx.x;
    const int b = bidx >> 6;
    const int rb = bidx & 63;
    const int h = rb >> 1;
    const int k0 = (rb & 1) * 32;
    const int hkv = h >> 2;

    // stage Q tile (32 queries x 128)
    {
        const int row = tid >> 3, j = tid & 7;
        const ushort_t* src = Qb + ((size_t)(b * 64 + k0 + row) * 4096 + h * 128 + j * 16);
        uint4 v0 = *(const uint4*)src;
        uint4 v1 = *(const uint4*)(src + 8);
        *(uint4*)&Qs[row * 136 + j * 16] = v0;
        *(uint4*)&Qs[row * 136 + j * 16 + 8] = v1;
    }
    if (tid < 32) { mst[tid] = -INFINITY; lst[tid] = 0.0f; }
    __syncthreads();

    bf16x8 aq[2][4];
    for (int mt = 0; mt < 2; mt++)
        for (int kk = 0; kk < 4; kk++)
            aq[mt][kk] = *(const bf16x8*)&Qs[(mt * 16 + (lane & 15)) * 136 + kk * 32 + quad * 8];

    f32x4 acc_o[2][2];
    for (int mt = 0; mt < 2; mt++)
        for (int nt = 0; nt < 2; nt++)
            acc_o[mt][nt] = (f32x4)0.0f;

    const float scale = 0.08838834764831845f;  // 1/sqrt(128)
    const int n0w = wid * 32;
    const int d0w = wid * 32;

    for (int ch = 0; ch < 33; ch++) {
        const int l0 = ch * 128;
        __syncthreads();

        // stage K chunk (128 l-rows x 128 d)
        {
            const int row = tid >> 1, half = tid & 1;
            const int lg = l0 + row;
            const ushort_t* src = Kc + ((size_t)(b * 4160 + lg) * 1024 + hkv * 128);
            const bool ok = lg < 4160;
            for (int i = 0; i < 8; i++) {
                const int ci = i * 2 + half;
                uint4 v = ok ? *(const uint4*)(src + ci * 8) : make_uint4(0, 0, 0, 0);
                *(uint4*)&Ks[row * 136 + ci * 8] = v;
            }
        }
        // stage V chunk transposed: Vts[d][l]
        for (int it = 0; it < 4; it++) {
            const int dg = wid + 4 * it;
            const int l = l0 + 2 * lane;
            const ushort_t* src = Vc + ((size_t)(b * 4160 + l) * 1024 + hkv * 128 + dg * 8);
            uint4 va = make_uint4(0, 0, 0, 0), vb = make_uint4(0, 0, 0, 0);
            if (l < 4160)     va = *(const uint4*)src;
            if (l + 1 < 4160) vb = *(const uint4*)(src + 1024);
            const ushort_t* ap = (const ushort_t*)&va;
            const ushort_t* bp = (const ushort_t*)&vb;
            for (int jj = 0; jj < 8; jj++) {
                unsigned int val = (unsigned int)ap[jj] | ((unsigned int)bp[jj] << 16);
                *(unsigned int*)&Vts[(dg * 8 + jj) * 136 + 2 * lane] = val;
            }
        }
        __syncthreads();

        // S = Q K^T
        f32x4 sacc[2][2];
        for (int mt = 0; mt < 2; mt++)
            for (int nt = 0; nt < 2; nt++)
                sacc[mt][nt] = (f32x4)0.0f;
        for (int kk = 0; kk < 4; kk++) {
            bf16x8 bk_[2];
            for (int nt = 0; nt < 2; nt++)
                bk_[nt] = *(const bf16x8*)&Ks[(n0w + nt * 16 + (lane & 15)) * 136 + kk * 32 + quad * 8];
            for (int mt = 0; mt < 2; mt++)
                for (int nt = 0; nt < 2; nt++)
                    sacc[mt][nt] = __builtin_amdgcn_mfma_f32_16x16x32_bf16(
                        aq[mt][kk], bk_[nt], sacc[mt][nt], 0, 0, 0);
        }
        for (int mt = 0; mt < 2; mt++) {
            for (int nt = 0; nt < 2; nt++) {
                const int col = n0w + nt * 16 + (lane & 15);
                const int l = l0 + col;
                for (int rr = 0; rr < 4; rr++) {
                    const int row = mt * 16 + quad * 4 + rr;
                    float s;
                    if (l < 4160) {
                        const float mk = amask[(size_t)(b * 64 + k0 + row) * 4160 + l];
                        s = sacc[mt][nt][rr] * scale + mk;
                    } else s = -3.0e4f;
                    Ss[row * 132 + col] = s;
                }
            }
        }
        __syncthreads();

        // online softmax: 8 lanes per row, 16 cols per lane
        {
            const int rw = wid * 8 + (lane >> 3);
            const int j = lane & 7;
            const float* srow = &Ss[rw * 132 + j * 16];
            float v[16];
            float mx = -INFINITY;
            for (int jj = 0; jj < 16; jj++) { v[jj] = srow[jj]; mx = fmaxf(mx, v[jj]); }
            mx = fmaxf(mx, __shfl_xor(mx, 1, 64));
            mx = fmaxf(mx, __shfl_xor(mx, 2, 64));
            mx = fmaxf(mx, __shfl_xor(mx, 4, 64));
            const float mo = mst[rw];
            const float mn = fmaxf(mo, mx);
            float sum = 0.0f;
            ushort_t pv[16];
            for (int jj = 0; jj < 16; jj++) {
                const float p = __expf(v[jj] - mn);
                sum += p;
                pv[jj] = f2bf(p);
            }
            sum += __shfl_xor(sum, 1, 64);
            sum += __shfl_xor(sum, 2, 64);
            sum += __shfl_xor(sum, 4, 64);
            const float a_ = __expf(mo - mn);
            if (j == 0) { mst[rw] = mn; lst[rw] = lst[rw] * a_ + sum; alp[rw] = a_; }
            for (int jj = 0; jj < 16; jj += 2) {
                unsigned int pk = (unsigned int)pv[jj] | ((unsigned int)pv[jj + 1] << 16);
                *(unsigned int*)&Ps[rw * 136 + j * 16 + jj] = pk;
            }
        }
        __syncthreads();

        // O = O*alpha + P V
        for (int mt = 0; mt < 2; mt++) {
            for (int nt = 0; nt < 2; nt++) {
                for (int rr = 0; rr < 4; rr++) {
                    const int row = mt * 16 + quad * 4 + rr;
                    acc_o[mt][nt][rr] *= alp[row];
                }
            }
        }
        for (int kk = 0; kk < 4; kk++) {
            bf16x8 ap_[2], bv[2];
            for (int mt = 0; mt < 2; mt++)
                ap_[mt] = *(const bf16x8*)&Ps[(mt * 16 + (lane & 15)) * 136 + kk * 32 + quad * 8];
            for (int nt = 0; nt < 2; nt++)
                bv[nt] = *(const bf16x8*)&Vts[(d0w + nt * 16 + (lane & 15)) * 136 + kk * 32 + quad * 8];
            for (int mt = 0; mt < 2; mt++)
                for (int nt = 0; nt < 2; nt++)
                    acc_o[mt][nt] = __builtin_amdgcn_mfma_f32_16x16x32_bf16(
                        ap_[mt], bv[nt], acc_o[mt][nt], 0, 0, 0);
        }
    }

    // epilogue: divide by l, store bf16 to AO (b,k, h*128+d)
    for (int mt = 0; mt < 2; mt++) {
        for (int nt = 0; nt < 2; nt++) {
            const int col = d0w + nt * 16 + (lane & 15);
            for (int rr = 0; rr < 4; rr++) {
                const int row = mt * 16 + quad * 4 + rr;
                AO[(size_t)(b * 64 + k0 + row) * 4096 + h * 128 + col] =
                    f2bf(acc_o[mt][nt][rr] / lst[row]);
            }
        }
    }
}

// ---------------------------------------------------------------------------

extern "C" void kernel_launch(void* const* d_in, const int* in_sizes, int n_in,
                              void* d_out, int out_size, void* d_ws, size_t ws_size,
                              hipStream_t stream) {
    const float* hs    = (const float*)d_in[0];   // hidden_states (4,64,4096) fp32
    const float* th    = (const float*)d_in[1];   // target_hidden (4,4096,4096) fp32
    const float* amask = (const float*)d_in[2];   // attn_mask (4,1,64,4160) fp32
    const float* cosb  = (const float*)d_in[3];   // cos (4,4160,128) fp32
    const float* sinb  = (const float*)d_in[4];   // sin fp32
    const float* Wq    = (const float*)d_in[5];   // (4096,4096) fp32
    const float* Wk    = (const float*)d_in[6];   // (1024,4096) fp32
    const float* Wv    = (const float*)d_in[7];   // (1024,4096) fp32
    const float* Wo    = (const float*)d_in[8];   // (4096,4096) fp32
    const float* qw    = (const float*)d_in[9];   // (128,) fp32
    const float* kw    = (const float*)d_in[10];  // (128,) fp32
    float* out = (float*)d_out;                   // (4,64,4096) fp32

    char* ws = (char*)d_ws;
    size_t off = 0;
    auto alloc = [&](size_t b) { char* p = ws + off; off += (b + 255) & ~(size_t)255; return p; };
    ushort_t* Kc  = (ushort_t*)alloc(34078720);   // (4,4160,1024) bf16
    ushort_t* Vc  = (ushort_t*)alloc(34078720);
    ushort_t* Qb  = (ushort_t*)alloc(2097152);    // (256,4096) bf16
    ushort_t* AOb = (ushort_t*)alloc(2097152);    // (256,4096) bf16
    ushort_t* hsb = (ushort_t*)alloc(2097152);    // hs bf16
    ushort_t* Wqb = (ushort_t*)alloc(33554432);
    ushort_t* Wkb = (ushort_t*)alloc(8388608);
    ushort_t* Wvb = (ushort_t*)alloc(8388608);
    ushort_t* Wob = (ushort_t*)alloc(33554432);

    // th bf16 staging: full buffer if workspace allows, else M-chunked
    int mrows;
    if      (ws_size >= off + (size_t)134217728) mrows = 16384;  // full (16384,4096)
    else if (ws_size >= off + (size_t)33554432)  mrows = 4096;   // 4 chunks
    else                                         mrows = 2048;   // 8 chunks
    ushort_t* thb = (ushort_t*)alloc((size_t)mrows * 4096 * 2);

    // 0) one-time bf16 conversions (weights + hs)
    cvt_bf16<<<dim3(1024), 256, 0, stream>>>(Wk, Wkb, 1024LL * 4096 / 8);
    cvt_bf16<<<dim3(1024), 256, 0, stream>>>(Wv, Wvb, 1024LL * 4096 / 8);
    cvt_bf16<<<dim3(2048), 256, 0, stream>>>(Wq, Wqb, 4096LL * 4096 / 8);
    cvt_bf16<<<dim3(2048), 256, 0, stream>>>(Wo, Wob, 4096LL * 4096 / 8);
    cvt_bf16<<<dim3(512),  256, 0, stream>>>(hs, hsb, 256LL * 4096 / 8);

    // 1) ctx K and V projections (dominant GEMM), bf16 path, chunked over M
    for (int c = 0; c < 16384 / mrows; ++c) {
        cvt_bf16<<<dim3(2048), 256, 0, stream>>>(
            th + (size_t)c * mrows * 4096, thb, (long long)mrows * 4096 / 8);
        gemm_bt_bf16<<<dim3(16, mrows / 128), 256, 0, stream>>>(thb, c * mrows,
            Wkb, Kc, 8, 1, 0,
            Wvb, Vc, 8, 1, 0,
            Wvb, Vc, 1, 0);
    }
    // 2) noise Q / K / V projections
    gemm_bt_bf16<<<dim3(48, 2), 256, 0, stream>>>(hsb, 0,
        Wqb, Qb, 32, 0, 4096,
        Wkb, Kc, 8, 2, 0,
        Wvb, Vc, 2, 0);
    // 3) rmsnorm + rope on K cache (all 4160 positions) and Q
    norm_rope<<<33280, 256, 0, stream>>>(Kc, cosb, sinb, kw, 0);
    norm_rope<<<2048, 256, 0, stream>>>(Qb, cosb, sinb, qw, 1);
    // 4) flash attention (bf16 output)
    attn_kernel<<<256, 256, 0, stream>>>(Qb, Kc, Vc, amask, AOb);
    // 5) output projection (bf16 A, fp32 out)
    gemm_bt_bf16<<<dim3(32, 2), 256, 0, stream>>>(AOb, 0,
        Wob, out, 32, 3, 4096,
        Wob, out, 0, 3, 4096,
        Wob, out, 3, 4096);
}

// Round 3
// 2856.102 us; speedup vs baseline: 1.6624x; 1.0285x over previous
//
#include <hip/hip_runtime.h>

typedef short bf16x8 __attribute__((ext_vector_type(8)));
typedef float f32x4 __attribute__((ext_vector_type(4)));
typedef unsigned short ushort_t;

__device__ inline float bf2f(ushort_t h) {
    return __uint_as_float(((unsigned int)h) << 16);
}
__device__ inline ushort_t f2bf(float f) {
    unsigned int u = __float_as_uint(f);
    unsigned int r = u + 0x7fffu + ((u >> 16) & 1u);   // RNE
    return (ushort_t)(r >> 16);
}

// async global->LDS, 16B per lane, LDS dest = wave-uniform base + lane*16
__device__ __forceinline__ void gload16(const ushort_t* g, ushort_t* l) {
    __builtin_amdgcn_global_load_lds(
        (const __attribute__((address_space(1))) unsigned int*)g,
        (__attribute__((address_space(3))) unsigned int*)l,
        16, 0, 0);
}

// ---------------------------------------------------------------------------
// fp32 -> bf16 bulk convert, 8 elems/thread/iter, grid-stride.
// ---------------------------------------------------------------------------
__global__ __launch_bounds__(256) void cvt_bf16(
    const float* __restrict__ s, ushort_t* __restrict__ d, long long n8)
{
    long long i = (long long)blockIdx.x * 256 + threadIdx.x;
    const long long stride = (long long)gridDim.x * 256;
    for (; i < n8; i += stride) {
        const float4 a = ((const float4*)s)[2 * i];
        const float4 b = ((const float4*)s)[2 * i + 1];
        uint4 o;
        o.x = (unsigned)f2bf(a.x) | ((unsigned)f2bf(a.y) << 16);
        o.y = (unsigned)f2bf(a.z) | ((unsigned)f2bf(a.w) << 16);
        o.z = (unsigned)f2bf(b.x) | ((unsigned)f2bf(b.y) << 16);
        o.w = (unsigned)f2bf(b.z) | ((unsigned)f2bf(b.w) << 16);
        ((uint4*)d)[i] = o;
    }
}

// ---------------------------------------------------------------------------
// C = A(MxK,bf16) * W(NxK,bf16)^T, bf16 MFMA, fp32 accumulate. K = 4096.
// 128x128 tile, BK=64, 256 threads, global_load_lds width=16.
// 2-PHASE DOUBLE-BUFFERED K-LOOP (catalog T3-minimum): stage tile t+1 into
// LDS buffer cur^1 BEFORE computing tile t from buffer cur; single
// __syncthreads() per step (compiler emits vmcnt(0)+lgkmcnt(0) drain there).
// LDS XOR swizzle via pre-swizzled global source (rule #21); reads use
// slot c16b^(row&7). XCD chunk swizzle, bm-fast within chunk so W-panels
// (2 MB) stay L2-resident while A streams.
// dest modes: 0 plain bf16 r*ldc+c; 1 ctx-cache bf16 (b=r>>12,t=r&4095 ->
//   (b*4160+t)*1024+c); 2 noise-cache bf16 (b=r>>6,k=r&63 ->
//   (b*4160+4096+k)*1024+c); 3 plain fp32 r*ldc+c.
// ---------------------------------------------------------------------------
__global__ __launch_bounds__(256, 2) void gemm_bt_bf16(
    const ushort_t* __restrict__ A, int roff,
    const ushort_t* __restrict__ W0, void* __restrict__ D0, int nb0, int mode0, int ldc0,
    const ushort_t* __restrict__ W1, void* __restrict__ D1, int nb1, int mode1, int ldc1,
    const ushort_t* __restrict__ W2, void* __restrict__ D2, int mode2, int ldc2)
{
    __shared__ __align__(16) ushort_t As[2][128 * 64];
    __shared__ __align__(16) ushort_t Bs[2][128 * 64];

    const int tid = threadIdx.x;
    const int lane = tid & 63;
    const int wid = tid >> 6;
    const int quad = lane >> 4;

    // bijective XCD-chunk swizzle (m204), bm-fast within chunk:
    // consecutive lin on one XCD share bn (W-panel hot in L2), sweep bm.
    const int gx = (int)gridDim.x;
    const int gy = (int)gridDim.y;
    const int nwg = gx * gy;
    const int flat = (int)blockIdx.y * gx + (int)blockIdx.x;
    const int q = nwg >> 3, r = nwg & 7;
    const int xcd = flat & 7, off = flat >> 3;
    const int lin = (xcd < r ? xcd * (q + 1) : r * (q + 1) + (xcd - r) * q) + off;
    const int bn = lin / gy;
    const int bm = lin % gy;

    const ushort_t* W; void* D; int mode, ldc, nloc;
    if (bn < nb0)            { W = W0; D = D0; mode = mode0; ldc = ldc0; nloc = bn; }
    else if (bn < nb0 + nb1) { W = W1; D = D1; mode = mode1; ldc = ldc1; nloc = bn - nb0; }
    else                     { W = W2; D = D2; mode = mode2; ldc = ldc2; nloc = bn - nb0 - nb1; }

    const int wm = wid >> 1, wn = wid & 1;
    const int srow = lane >> 3;                    // row within 8-row LDS chunk
    const int scs  = ((lane & 7) ^ srow) * 8;      // swizzled source col (bf16 units)

    const ushort_t* Abase = A + (size_t)(bm * 128) * 4096;
    const ushort_t* Wbase = W + (size_t)(nloc * 128) * 4096;

    f32x4 acc[4][4];
    for (int mt = 0; mt < 4; mt++)
        for (int nt = 0; nt < 4; nt++)
            acc[mt][nt] = (f32x4)0.0f;

    // stage K-tile k0 into buffer buf
    auto stage = [&](int buf, int k0) {
        for (int i = 0; i < 4; i++) {
            const int chunk = wid * 4 + i;          // 0..15 (1 KB LDS each)
            const int row = chunk * 8 + srow;       // 0..127
            gload16(Abase + (size_t)row * 4096 + k0 + scs, &As[buf][chunk * 512]);
            gload16(Wbase + (size_t)row * 4096 + k0 + scs, &Bs[buf][chunk * 512]);
        }
    };

    stage(0, 0);
    __syncthreads();   // drains vmcnt(0): buffer 0 ready

    for (int t = 0; t < 64; t++) {
        const int cur = t & 1;
        if (t + 1 < 64) stage(cur ^ 1, (t + 1) * 64);   // prefetch next tile
        for (int kk = 0; kk < 2; kk++) {
            const int c16b = kk * 4 + quad;
            bf16x8 af[4], bfv[4];
            for (int mt = 0; mt < 4; mt++) {
                const int rm = wm * 64 + mt * 16 + (lane & 15);
                af[mt] = *(const bf16x8*)&As[cur][rm * 64 + ((c16b ^ (rm & 7)) * 8)];
            }
            for (int nt = 0; nt < 4; nt++) {
                const int rn = wn * 64 + nt * 16 + (lane & 15);
                bfv[nt] = *(const bf16x8*)&Bs[cur][rn * 64 + ((c16b ^ (rn & 7)) * 8)];
            }
            for (int mt = 0; mt < 4; mt++)
                for (int nt = 0; nt < 4; nt++)
                    acc[mt][nt] = __builtin_amdgcn_mfma_f32_16x16x32_bf16(
                        af[mt], bfv[nt], acc[mt][nt], 0, 0, 0);
        }
        __syncthreads();   // one barrier/step: drains prefetch, protects cur
    }

    for (int mt = 0; mt < 4; mt++) {
        for (int nt = 0; nt < 4; nt++) {
            const int c = nloc * 128 + wn * 64 + nt * 16 + (lane & 15);
            for (int rr = 0; rr < 4; rr++) {
                const int r = roff + bm * 128 + wm * 64 + mt * 16 + quad * 4 + rr;
                const float val = acc[mt][nt][rr];
                if (mode == 0) {
                    ((ushort_t*)D)[(size_t)r * ldc + c] = f2bf(val);
                } else if (mode == 1) {
                    int b = r >> 12, t2 = r & 4095;
                    ((ushort_t*)D)[((size_t)(b * 4160 + t2)) * 1024 + c] = f2bf(val);
                } else if (mode == 2) {
                    int b = r >> 6, kq = r & 63;
                    ((ushort_t*)D)[((size_t)(b * 4160 + 4096 + kq)) * 1024 + c] = f2bf(val);
                } else {
                    ((float*)D)[(size_t)r * ldc + c] = val;
                }
            }
        }
    }
}

// ---------------------------------------------------------------------------
// RMSNorm + RoPE, in place on bf16 buffers, one wave per 128-dim head row.
// ---------------------------------------------------------------------------
__global__ __launch_bounds__(256) void norm_rope(
    ushort_t* __restrict__ X,
    const float* __restrict__ cosb, const float* __restrict__ sinb,
    const float* __restrict__ w, int mode)
{
    const int lane = threadIdx.x & 63;
    const int wid = threadIdx.x >> 6;
    const int rid = blockIdx.x * 4 + wid;

    ushort_t* ptr;
    size_t pos_row;
    if (mode == 0) {
        const int h = rid & 7, tmp = rid >> 3;      // tmp = b*4160 + l
        ptr = X + (size_t)tmp * 1024 + h * 128;
        pos_row = (size_t)tmp;
    } else {
        const int h = rid & 31, tmp = rid >> 5;     // tmp = b*64 + k
        const int k = tmp & 63, b = tmp >> 6;
        ptr = X + (size_t)tmp * 4096 + h * 128;
        pos_row = (size_t)(b * 4160 + 4096 + k);
    }

    float x1 = bf2f(ptr[lane]);
    float x2 = bf2f(ptr[lane + 64]);
    float ss = x1 * x1 + x2 * x2;
    for (int m = 1; m < 64; m <<= 1) ss += __shfl_xor(ss, m, 64);
    const float rn = rsqrtf(ss * (1.0f / 128.0f) + 1e-6f);
    const float y1 = x1 * rn * w[lane];
    const float y2 = x2 * rn * w[lane + 64];

    const float* cr = cosb + pos_row * 128;
    const float* sr = sinb + pos_row * 128;
    ptr[lane]      = f2bf(y1 * cr[lane]      - y2 * sr[lane]);
    ptr[lane + 64] = f2bf(y2 * cr[lane + 64] + y1 * sr[lane + 64]);
}

// ---------------------------------------------------------------------------
// Flash attention: one block = (b, head h, 32-query half), 256 blocks, 256 thr.
// Output AO bf16.
// ---------------------------------------------------------------------------
__global__ __launch_bounds__(256) void attn_kernel(
    const ushort_t* __restrict__ Qb, const ushort_t* __restrict__ Kc,
    const ushort_t* __restrict__ Vc, const float* __restrict__ amask,
    ushort_t* __restrict__ AO)
{
    __shared__ __align__(16) ushort_t Qs[32 * 136];
    __shared__ __align__(16) ushort_t Ks[128 * 136];
    __shared__ __align__(16) ushort_t Vts[128 * 136];   // transposed: [d][l]
    __shared__ __align__(16) ushort_t Ps[32 * 136];
    __shared__ __align__(16) float Ss[32 * 132];
    __shared__ float mst[32], lst[32], alp[32];

    const int tid = threadIdx.x;
    const int lane = tid & 63;
    const int wid = tid >> 6;
    const int quad = lane >> 4;

    const int bidx = blockIdx.x;
    const int b = bidx >> 6;
    const int rb = bidx & 63;
    const int h = rb >> 1;
    const int k0 = (rb & 1) * 32;
    const int hkv = h >> 2;

    // stage Q tile (32 queries x 128)
    {
        const int row = tid >> 3, j = tid & 7;
        const ushort_t* src = Qb + ((size_t)(b * 64 + k0 + row) * 4096 + h * 128 + j * 16);
        uint4 v0 = *(const uint4*)src;
        uint4 v1 = *(const uint4*)(src + 8);
        *(uint4*)&Qs[row * 136 + j * 16] = v0;
        *(uint4*)&Qs[row * 136 + j * 16 + 8] = v1;
    }
    if (tid < 32) { mst[tid] = -INFINITY; lst[tid] = 0.0f; }
    __syncthreads();

    bf16x8 aq[2][4];
    for (int mt = 0; mt < 2; mt++)
        for (int kk = 0; kk < 4; kk++)
            aq[mt][kk] = *(const bf16x8*)&Qs[(mt * 16 + (lane & 15)) * 136 + kk * 32 + quad * 8];

    f32x4 acc_o[2][2];
    for (int mt = 0; mt < 2; mt++)
        for (int nt = 0; nt < 2; nt++)
            acc_o[mt][nt] = (f32x4)0.0f;

    const float scale = 0.08838834764831845f;  // 1/sqrt(128)
    const int n0w = wid * 32;
    const int d0w = wid * 32;

    for (int ch = 0; ch < 33; ch++) {
        const int l0 = ch * 128;
        __syncthreads();

        // stage K chunk (128 l-rows x 128 d)
        {
            const int row = tid >> 1, half = tid & 1;
            const int lg = l0 + row;
            const ushort_t* src = Kc + ((size_t)(b * 4160 + lg) * 1024 + hkv * 128);
            const bool ok = lg < 4160;
            for (int i = 0; i < 8; i++) {
                const int ci = i * 2 + half;
                uint4 v = ok ? *(const uint4*)(src + ci * 8) : make_uint4(0, 0, 0, 0);
                *(uint4*)&Ks[row * 136 + ci * 8] = v;
            }
        }
        // stage V chunk transposed: Vts[d][l]
        for (int it = 0; it < 4; it++) {
            const int dg = wid + 4 * it;
            const int l = l0 + 2 * lane;
            const ushort_t* src = Vc + ((size_t)(b * 4160 + l) * 1024 + hkv * 128 + dg * 8);
            uint4 va = make_uint4(0, 0, 0, 0), vb = make_uint4(0, 0, 0, 0);
            if (l < 4160)     va = *(const uint4*)src;
            if (l + 1 < 4160) vb = *(const uint4*)(src + 1024);
            const ushort_t* ap = (const ushort_t*)&va;
            const ushort_t* bp = (const ushort_t*)&vb;
            for (int jj = 0; jj < 8; jj++) {
                unsigned int val = (unsigned int)ap[jj] | ((unsigned int)bp[jj] << 16);
                *(unsigned int*)&Vts[(dg * 8 + jj) * 136 + 2 * lane] = val;
            }
        }
        __syncthreads();

        // S = Q K^T
        f32x4 sacc[2][2];
        for (int mt = 0; mt < 2; mt++)
            for (int nt = 0; nt < 2; nt++)
                sacc[mt][nt] = (f32x4)0.0f;
        for (int kk = 0; kk < 4; kk++) {
            bf16x8 bk_[2];
            for (int nt = 0; nt < 2; nt++)
                bk_[nt] = *(const bf16x8*)&Ks[(n0w + nt * 16 + (lane & 15)) * 136 + kk * 32 + quad * 8];
            for (int mt = 0; mt < 2; mt++)
                for (int nt = 0; nt < 2; nt++)
                    sacc[mt][nt] = __builtin_amdgcn_mfma_f32_16x16x32_bf16(
                        aq[mt][kk], bk_[nt], sacc[mt][nt], 0, 0, 0);
        }
        for (int mt = 0; mt < 2; mt++) {
            for (int nt = 0; nt < 2; nt++) {
                const int col = n0w + nt * 16 + (lane & 15);
                const int l = l0 + col;
                for (int rr = 0; rr < 4; rr++) {
                    const int row = mt * 16 + quad * 4 + rr;
                    float s;
                    if (l < 4160) {
                        const float mk = amask[(size_t)(b * 64 + k0 + row) * 4160 + l];
                        s = sacc[mt][nt][rr] * scale + mk;
                    } else s = -3.0e4f;
                    Ss[row * 132 + col] = s;
                }
            }
        }
        __syncthreads();

        // online softmax: 8 lanes per row, 16 cols per lane
        {
            const int rw = wid * 8 + (lane >> 3);
            const int j = lane & 7;
            const float* srow = &Ss[rw * 132 + j * 16];
            float v[16];
            float mx = -INFINITY;
            for (int jj = 0; jj < 16; jj++) { v[jj] = srow[jj]; mx = fmaxf(mx, v[jj]); }
            mx = fmaxf(mx, __shfl_xor(mx, 1, 64));
            mx = fmaxf(mx, __shfl_xor(mx, 2, 64));
            mx = fmaxf(mx, __shfl_xor(mx, 4, 64));
            const float mo = mst[rw];
            const float mn = fmaxf(mo, mx);
            float sum = 0.0f;
            ushort_t pv[16];
            for (int jj = 0; jj < 16; jj++) {
                const float p = __expf(v[jj] - mn);
                sum += p;
                pv[jj] = f2bf(p);
            }
            sum += __shfl_xor(sum, 1, 64);
            sum += __shfl_xor(sum, 2, 64);
            sum += __shfl_xor(sum, 4, 64);
            const float a_ = __expf(mo - mn);
            if (j == 0) { mst[rw] = mn; lst[rw] = lst[rw] * a_ + sum; alp[rw] = a_; }
            for (int jj = 0; jj < 16; jj += 2) {
                unsigned int pk = (unsigned int)pv[jj] | ((unsigned int)pv[jj + 1] << 16);
                *(unsigned int*)&Ps[rw * 136 + j * 16 + jj] = pk;
            }
        }
        __syncthreads();

        // O = O*alpha + P V
        for (int mt = 0; mt < 2; mt++) {
            for (int nt = 0; nt < 2; nt++) {
                for (int rr = 0; rr < 4; rr++) {
                    const int row = mt * 16 + quad * 4 + rr;
                    acc_o[mt][nt][rr] *= alp[row];
                }
            }
        }
        for (int kk = 0; kk < 4; kk++) {
            bf16x8 ap_[2], bv[2];
            for (int mt = 0; mt < 2; mt++)
                ap_[mt] = *(const bf16x8*)&Ps[(mt * 16 + (lane & 15)) * 136 + kk * 32 + quad * 8];
            for (int nt = 0; nt < 2; nt++)
                bv[nt] = *(const bf16x8*)&Vts[(d0w + nt * 16 + (lane & 15)) * 136 + kk * 32 + quad * 8];
            for (int mt = 0; mt < 2; mt++)
                for (int nt = 0; nt < 2; nt++)
                    acc_o[mt][nt] = __builtin_amdgcn_mfma_f32_16x16x32_bf16(
                        ap_[mt], bv[nt], acc_o[mt][nt], 0, 0, 0);
        }
    }

    // epilogue: divide by l, store bf16 to AO (b,k, h*128+d)
    for (int mt = 0; mt < 2; mt++) {
        for (int nt = 0; nt < 2; nt++) {
            const int col = d0w + nt * 16 + (lane & 15);
            for (int rr = 0; rr < 4; rr++) {
                const int row = mt * 16 + quad * 4 + rr;
                AO[(size_t)(b * 64 + k0 + row) * 4096 + h * 128 + col] =
                    f2bf(acc_o[mt][nt][rr] / lst[row]);
            }
        }
    }
}

// ---------------------------------------------------------------------------

extern "C" void kernel_launch(void* const* d_in, const int* in_sizes, int n_in,
                              void* d_out, int out_size, void* d_ws, size_t ws_size,
                              hipStream_t stream) {
    const float* hs    = (const float*)d_in[0];   // hidden_states (4,64,4096) fp32
    const float* th    = (const float*)d_in[1];   // target_hidden (4,4096,4096) fp32
    const float* amask = (const float*)d_in[2];   // attn_mask (4,1,64,4160) fp32
    const float* cosb  = (const float*)d_in[3];   // cos (4,4160,128) fp32
    const float* sinb  = (const float*)d_in[4];   // sin fp32
    const float* Wq    = (const float*)d_in[5];   // (4096,4096) fp32
    const float* Wk    = (const float*)d_in[6];   // (1024,4096) fp32
    const float* Wv    = (const float*)d_in[7];   // (1024,4096) fp32
    const float* Wo    = (const float*)d_in[8];   // (4096,4096) fp32
    const float* qw    = (const float*)d_in[9];   // (128,) fp32
    const float* kw    = (const float*)d_in[10];  // (128,) fp32
    float* out = (float*)d_out;                   // (4,64,4096) fp32

    char* ws = (char*)d_ws;
    size_t off = 0;
    auto alloc = [&](size_t b) { char* p = ws + off; off += (b + 255) & ~(size_t)255; return p; };
    ushort_t* Kc  = (ushort_t*)alloc(34078720);   // (4,4160,1024) bf16
    ushort_t* Vc  = (ushort_t*)alloc(34078720);
    ushort_t* Qb  = (ushort_t*)alloc(2097152);    // (256,4096) bf16
    ushort_t* AOb = (ushort_t*)alloc(2097152);    // (256,4096) bf16
    ushort_t* hsb = (ushort_t*)alloc(2097152);    // hs bf16
    ushort_t* Wqb = (ushort_t*)alloc(33554432);
    ushort_t* Wkb = (ushort_t*)alloc(8388608);
    ushort_t* Wvb = (ushort_t*)alloc(8388608);
    ushort_t* Wob = (ushort_t*)alloc(33554432);

    // th bf16 staging: full buffer if workspace allows, else M-chunked
    int mrows;
    if      (ws_size >= off + (size_t)134217728) mrows = 16384;  // full (16384,4096)
    else if (ws_size >= off + (size_t)33554432)  mrows = 4096;   // 4 chunks
    else                                         mrows = 2048;   // 8 chunks
    ushort_t* thb = (ushort_t*)alloc((size_t)mrows * 4096 * 2);

    // 0) one-time bf16 conversions (weights + hs)
    cvt_bf16<<<dim3(1024), 256, 0, stream>>>(Wk, Wkb, 1024LL * 4096 / 8);
    cvt_bf16<<<dim3(1024), 256, 0, stream>>>(Wv, Wvb, 1024LL * 4096 / 8);
    cvt_bf16<<<dim3(2048), 256, 0, stream>>>(Wq, Wqb, 4096LL * 4096 / 8);
    cvt_bf16<<<dim3(2048), 256, 0, stream>>>(Wo, Wob, 4096LL * 4096 / 8);
    cvt_bf16<<<dim3(512),  256, 0, stream>>>(hs, hsb, 256LL * 4096 / 8);

    // 1) ctx K and V projections (dominant GEMM), bf16 path, chunked over M
    for (int c = 0; c < 16384 / mrows; ++c) {
        cvt_bf16<<<dim3(2048), 256, 0, stream>>>(
            th + (size_t)c * mrows * 4096, thb, (long long)mrows * 4096 / 8);
        gemm_bt_bf16<<<dim3(16, mrows / 128), 256, 0, stream>>>(thb, c * mrows,
            Wkb, Kc, 8, 1, 0,
            Wvb, Vc, 8, 1, 0,
            Wvb, Vc, 1, 0);
    }
    // 2) noise Q / K / V projections
    gemm_bt_bf16<<<dim3(48, 2), 256, 0, stream>>>(hsb, 0,
        Wqb, Qb, 32, 0, 4096,
        Wkb, Kc, 8, 2, 0,
        Wvb, Vc, 2, 0);
    // 3) rmsnorm + rope on K cache (all 4160 positions) and Q
    norm_rope<<<33280, 256, 0, stream>>>(Kc, cosb, sinb, kw, 0);
    norm_rope<<<2048, 256, 0, stream>>>(Qb, cosb, sinb, qw, 1);
    // 4) flash attention (bf16 output)
    attn_kernel<<<256, 256, 0, stream>>>(Qb, Kc, Vc, amask, AOb);
    // 5) output projection (bf16 A, fp32 out)
    gemm_bt_bf16<<<dim3(32, 2), 256, 0, stream>>>(AOb, 0,
        Wob, out, 32, 3, 4096,
        Wob, out, 0, 3, 4096,
        Wob, out, 3, 4096);
}